// Round 5
// baseline (487.882 us; speedup 1.0000x reference)
//
#include <hip/hip_runtime.h>
#include <hip/hip_bf16.h>
#include <stdint.h>

// ---------------------------------------------------------------------------
// MetaMultiHeadSelfAttention: B=4, S=2048, D=1024, H=16, hd=64, causal.
// R5 == R3 resubmit #2 (two infra failures in a row; kernel never ran):
// causal-paired q-tiles (64-row tiles, block j handles tiles j and 31-j
// -> uniform 33 K-tiles/block, kills the drain tail behind R2's 12% occupancy).
// S^T-form attention, no-max softmax, barrier-free K-loop, direct gathers.
// m97-style GEMMs (global_load_lds + XOR swizzle), fused QKV projection.
// ---------------------------------------------------------------------------

typedef __bf16 bf16x8 __attribute__((ext_vector_type(8)));
typedef __bf16 bf16x4 __attribute__((ext_vector_type(4)));
typedef float  f32x4  __attribute__((ext_vector_type(4)));

static __device__ __forceinline__ f32x4 mfma16(bf16x8 a, bf16x8 b, f32x4 c) {
  return __builtin_amdgcn_mfma_f32_16x16x32_bf16(a, b, c, 0, 0, 0);
}

// async 16B/lane global->LDS; LDS dest = wave-uniform base + lane*16
static __device__ __forceinline__ void load16_lds(const void* g, void* l) {
  __builtin_amdgcn_global_load_lds(
      (const __attribute__((address_space(1))) unsigned int*)g,
      (__attribute__((address_space(3))) unsigned int*)l, 16, 0, 0);
}

// ---------------------------------------------------------------------------
// fp32 -> bf16, 8 elems/thread
// ---------------------------------------------------------------------------
__global__ __launch_bounds__(256) void cvt_f32_bf16(
    const float* __restrict__ in, __bf16* __restrict__ out, int n8) {
  int i = blockIdx.x * blockDim.x + threadIdx.x;
  if (i >= n8) return;
  const float4* in4 = (const float4*)in;
  float4 a = in4[2 * i], b = in4[2 * i + 1];
  __bf16 v[8];
  v[0] = (__bf16)a.x; v[1] = (__bf16)a.y; v[2] = (__bf16)a.z; v[3] = (__bf16)a.w;
  v[4] = (__bf16)b.x; v[5] = (__bf16)b.y; v[6] = (__bf16)b.z; v[7] = (__bf16)b.w;
  *(bf16x8*)(out + 8 * i) = *(bf16x8*)v;
}

// all 4 weight matrices in one launch: wq,wk,wv -> wqkv rows, wo -> wob
__global__ __launch_bounds__(256) void cvt_w(
    const float* __restrict__ w0, const float* __restrict__ w1,
    const float* __restrict__ w2, const float* __restrict__ w3,
    __bf16* __restrict__ wqkv, __bf16* __restrict__ wo) {
  int blk = blockIdx.x;                 // 2048 blocks, 512 per matrix
  int m = blk >> 9;
  const float* src = (m == 0) ? w0 : (m == 1) ? w1 : (m == 2) ? w2 : w3;
  __bf16* dst = (m < 3) ? (wqkv + (size_t)m * (1024 * 1024)) : wo;
  int i = (blk & 511) * 256 + threadIdx.x;
  const float4* in4 = (const float4*)src;
  float4 a = in4[2 * i], b = in4[2 * i + 1];
  __bf16 v[8];
  v[0] = (__bf16)a.x; v[1] = (__bf16)a.y; v[2] = (__bf16)a.z; v[3] = (__bf16)a.w;
  v[4] = (__bf16)b.x; v[5] = (__bf16)b.y; v[6] = (__bf16)b.z; v[7] = (__bf16)b.w;
  *(bf16x8*)(dst + 8 * i) = *(bf16x8*)v;
}

// ---------------------------------------------------------------------------
// C[M,N] = A[M,K] @ Bw[N,K]^T, m97 pattern: 128x128 tile, BK=32,
// global_load_lds width=16 into unpadded LDS [128][32] with XOR chunk swizzle.
// ---------------------------------------------------------------------------
template <typename OutT>
__global__ __launch_bounds__(256) void gemm_bt2(
    const __bf16* __restrict__ A, const __bf16* __restrict__ Bw,
    OutT* __restrict__ C, int M, int N, int K) {
  __shared__ __align__(16) __bf16 As[128 * 32];
  __shared__ __align__(16) __bf16 Bs[128 * 32];
  const int t = threadIdx.x;
  const int lane = t & 63, w = t >> 6;
  const int wm = w >> 1, wn = w & 1;
  const int l15 = lane & 15, quad = lane >> 4;
  const long rowA0 = (long)blockIdx.y * 128;
  const long rowB0 = (long)blockIdx.x * 128;

  const int r0 = w * 32 + (lane >> 2);
  const int r1 = r0 + 16;
  const int c0 = (lane & 3) ^ ((r0 >> 1) & 3);
  const int c1 = (lane & 3) ^ ((r1 >> 1) & 3);
  const __bf16* pA0 = A + (rowA0 + r0) * (long)K + c0 * 8;
  const __bf16* pA1 = A + (rowA0 + r1) * (long)K + c1 * 8;
  const __bf16* pB0 = Bw + (rowB0 + r0) * (long)K + c0 * 8;
  const __bf16* pB1 = Bw + (rowB0 + r1) * (long)K + c1 * 8;
  __bf16* lA0 = As + (w * 32) * 32;
  __bf16* lA1 = As + (w * 32 + 16) * 32;
  __bf16* lB0 = Bs + (w * 32) * 32;
  __bf16* lB1 = Bs + (w * 32 + 16) * 32;

  int aoff[4], boff[4];
#pragma unroll
  for (int i = 0; i < 4; i++) {
    int Ra = wm * 64 + i * 16 + l15;
    aoff[i] = Ra * 32 + ((quad ^ ((Ra >> 1) & 3)) << 3);
    int Rb = wn * 64 + i * 16 + l15;
    boff[i] = Rb * 32 + ((quad ^ ((Rb >> 1) & 3)) << 3);
  }

  f32x4 acc[4][4] = {};
  for (int k0 = 0; k0 < K; k0 += 32) {
    load16_lds(pA0, lA0); load16_lds(pA1, lA1);
    load16_lds(pB0, lB0); load16_lds(pB1, lB1);
    pA0 += 32; pA1 += 32; pB0 += 32; pB1 += 32;
    __syncthreads();
    bf16x8 af[4], bfr[4];
#pragma unroll
    for (int i = 0; i < 4; i++) af[i] = *(const bf16x8*)(As + aoff[i]);
#pragma unroll
    for (int i = 0; i < 4; i++) bfr[i] = *(const bf16x8*)(Bs + boff[i]);
#pragma unroll
    for (int mt = 0; mt < 4; mt++)
#pragma unroll
      for (int nt = 0; nt < 4; nt++)
        acc[mt][nt] = mfma16(af[mt], bfr[nt], acc[mt][nt]);
    __syncthreads();
  }

#pragma unroll
  for (int mt = 0; mt < 4; mt++)
#pragma unroll
    for (int nt = 0; nt < 4; nt++)
#pragma unroll
      for (int r = 0; r < 4; r++) {
        long row = rowA0 + wm * 64 + mt * 16 + quad * 4 + r;
        long col = rowB0 + wn * 64 + nt * 16 + l15;
        float v = acc[mt][nt][r];
        if constexpr (sizeof(OutT) == 2) C[row * N + col] = (OutT)(__bf16)v;
        else                             C[row * N + col] = v;
      }
}

// ---------------------------------------------------------------------------
// V transpose: QKV[b][s][2048 + h*64 + d] -> VT[(b*16+h)*64 + d][s]
// ---------------------------------------------------------------------------
__global__ __launch_bounds__(256) void vtrans(
    const __bf16* __restrict__ QKV, __bf16* __restrict__ VT) {
  constexpr int LDs = 136;
  __shared__ __align__(16) __bf16 Ts[64 * LDs];
  const int t = threadIdx.x;
  const int st0 = blockIdx.x * 128, h = blockIdx.y, b = blockIdx.z;
  const long vbase = (long)b * 2048 * 3072 + 2048 + h * 64;
#pragma unroll
  for (int i = 0; i < 4; i++) {
    int sl = i * 32 + (t >> 3), d0 = (t & 7) * 8;
    __bf16 tmp[8];
    *(uint4*)tmp = *(const uint4*)(QKV + vbase + (long)(st0 + sl) * 3072 + d0);
#pragma unroll
    for (int j = 0; j < 8; j++) Ts[(d0 + j) * LDs + sl] = tmp[j];
  }
  __syncthreads();
  const long obase = (long)(b * 16 + h) * 64 * 2048 + st0;
  const int d = t >> 2;
#pragma unroll
  for (int i = 0; i < 4; i++) {
    int sc = ((t & 3) + 4 * i) * 8;
    *(uint4*)(VT + obase + (long)d * 2048 + sc) = *(const uint4*)(Ts + d * LDs + sc);
  }
}

// ---------------------------------------------------------------------------
// Causal attention, paired q-tiles for uniform work.
// 64-row q-tiles (32 per b,h). Block j processes tile j then tile 31-j:
// (j+1) + (32-j) = 33 K-tiles for EVERY block -> no drain tail.
// 4 waves x 16 q-rows per strip. S^T form (A=K m=key, B=Q n=qrow),
// no-max softmax, packed 8B P writes to wave-private LDS, no barriers.
// ---------------------------------------------------------------------------
__global__ __launch_bounds__(256) void attn3(
    const __bf16* __restrict__ QKV, const __bf16* __restrict__ VT,
    __bf16* __restrict__ O) {
  constexpr int SD = 3072;
  constexpr int LDP = 72;
  __shared__ __align__(16) __bf16 Pw[4 * 16 * LDP];
  const int t = threadIdx.x;
  const int lane = t & 63, w = t >> 6;
  const int l15 = lane & 15, quad = lane >> 4;
  const int j = blockIdx.x, h = blockIdx.y, b = blockIdx.z;
  const long qbase = (long)b * 2048 * SD + h * 64;
  const long kbase = qbase + 1024;
  const long vtbase = (long)(b * 16 + h) * 64 * 2048;
  __bf16* Pme = Pw + w * 16 * LDP;

#pragma unroll
  for (int half = 0; half < 2; half++) {
    const int qt = half ? (31 - j) : j;
    const int row0 = qt * 64 + w * 16;      // this wave's 16-row strip

    // Q fragments (B-operand: n = qrow = l15)
    bf16x8 qf[2];
#pragma unroll
    for (int kk = 0; kk < 2; kk++)
      qf[kk] = *(const bf16x8*)(QKV + qbase +
          (long)(row0 + l15) * SD + kk * 32 + quad * 8);

    f32x4 o_acc[4] = {};
    float l_part = 0.f;

    for (int kt = 0; kt <= qt; kt++) {
      const int k0 = kt * 64;
      // K fragments (A-operand: m = key = l15 within 16-row group)
      bf16x8 kf[4][2];
#pragma unroll
      for (int nt = 0; nt < 4; nt++)
#pragma unroll
        for (int kk = 0; kk < 2; kk++)
          kf[nt][kk] = *(const bf16x8*)(QKV + kbase +
              (long)(k0 + nt * 16 + l15) * SD + kk * 32 + quad * 8);
      // V^T fragments (B-operand: n = d = l15), issue early
      bf16x8 vf[4][2];
#pragma unroll
      for (int dt = 0; dt < 4; dt++)
#pragma unroll
        for (int kk = 0; kk < 2; kk++)
          vf[dt][kk] = *(const bf16x8*)(VT + vtbase +
              (long)(dt * 16 + l15) * 2048 + k0 + kk * 32 + quad * 8);
      // S^T = K Q^T : lane holds key = nt*16 + quad*4 + r, qrow = l15
      f32x4 st[4];
#pragma unroll
      for (int nt = 0; nt < 4; nt++) {
        f32x4 z = {0.f, 0.f, 0.f, 0.f};
        z = mfma16(kf[nt][0], qf[0], z);
        st[nt] = mfma16(kf[nt][1], qf[1], z);
      }
      // exp + lane-local l partial + packed P write (4 consecutive keys, 8B)
      const bool needmask = (kt == qt);
      const int qrow = row0 + l15;
#pragma unroll
      for (int nt = 0; nt < 4; nt++) {
        const int keyb = k0 + nt * 16 + quad * 4;
        bf16x4 pb;
#pragma unroll
        for (int r = 0; r < 4; r++) {
          float e = __expf(st[nt][r] * 0.125f);
          if (needmask && (keyb + r > qrow)) e = 0.f;
          l_part += e;
          pb[r] = (__bf16)e;
        }
        *(bf16x4*)(Pme + l15 * LDP + nt * 16 + quad * 4) = pb;
      }
      // PV: O += P V (same-wave LDS RAW)
#pragma unroll
      for (int kk = 0; kk < 2; kk++) {
        bf16x8 pf = *(const bf16x8*)(Pme + l15 * LDP + kk * 32 + quad * 8);
#pragma unroll
        for (int dt = 0; dt < 4; dt++)
          o_acc[dt] = mfma16(pf, vf[dt][kk], o_acc[dt]);
      }
    }

    // epilogue: l = sum over quads; normalize; write O
    float l = l_part;
    l += __shfl_xor(l, 16, 64);
    l += __shfl_xor(l, 32, 64);           // lane now holds l for qrow = l15
#pragma unroll
    for (int r = 0; r < 4; r++) {
      float lr = __shfl(l, quad * 4 + r, 64);
      float inv = 1.f / lr;
      int row = row0 + quad * 4 + r;
      long ob = ((long)b * 2048 + row) * 1024 + h * 64;
#pragma unroll
      for (int dt = 0; dt < 4; dt++)
        O[ob + dt * 16 + l15] = (__bf16)(o_acc[dt][r] * inv);
    }
  }
}

// ---------------------------------------------------------------------------
extern "C" void kernel_launch(void* const* d_in, const int* in_sizes, int n_in,
                              void* d_out, int out_size, void* d_ws, size_t ws_size,
                              hipStream_t stream) {
  const float* x  = (const float*)d_in[0];
  const float* wq = (const float*)d_in[1];
  const float* wk = (const float*)d_in[2];
  const float* wv = (const float*)d_in[3];
  const float* wo = (const float*)d_in[4];
  float* out = (float*)d_out;

  char* ws = (char*)d_ws;
  __bf16* xb   = (__bf16*)(ws);               // 16 MB [8192,1024]; reused as Ab
  __bf16* wqkv = (__bf16*)(ws + (16l << 20)); //  6 MB [3072,1024]
  __bf16* wob  = (__bf16*)(ws + (22l << 20)); //  2 MB
  __bf16* QKV  = (__bf16*)(ws + (24l << 20)); // 48 MB [8192,3072]
  __bf16* VT   = (__bf16*)(ws + (72l << 20)); // 16 MB [4096,2048] -> 88 MB total
  __bf16* Ab   = xb;                          // x dead after QKV gemm

  cvt_f32_bf16<<<4096, 256, 0, stream>>>(x, xb, 8192 * 1024 / 8);
  cvt_w<<<2048, 256, 0, stream>>>(wq, wk, wv, wo, wqkv, wob);

  // fused QKV projection: [8192,3072] = xb @ wqkv^T
  gemm_bt2<__bf16><<<dim3(24, 64), 256, 0, stream>>>(xb, wqkv, QKV, 8192, 3072, 1024);

  // V -> VT [b,h,d,s]
  vtrans<<<dim3(16, 16, 4), 256, 0, stream>>>(QKV, VT);

  // causal attention (paired tiles) -> Ab [b,s,h*64+d]
  attn3<<<dim3(16, 16, 4), 256, 0, stream>>>(QKV, VT, Ab);

  // output projection (fp32 out)
  gemm_bt2<float><<<dim3(8, 64), 256, 0, stream>>>(Ab, wob, out, 8192, 1024, 1024);
}

// Round 7
// 277.620 us; speedup vs baseline: 1.7574x; 1.7574x over previous
//
#include <hip/hip_runtime.h>
#include <hip/hip_bf16.h>
#include <stdint.h>

// ---------------------------------------------------------------------------
// MetaMultiHeadSelfAttention: B=4, S=2048, D=1024, H=16, hd=64, causal.
// R7 == R6 resubmit (container infra failure; kernel never ran):
// attention with LDS-staged K/VT tiles (global_load_lds + XOR swizzle,
// shared by all 4 waves — kills R5's 2.2 GB divergent gather volume),
// 128-row q-tiles (32 rows/wave), causal pairing (j, 15-j) -> uniform
// 34 K-tiles/block, 512 blocks. S^T-form MFMA, no-max softmax.
// m97-style GEMMs, fused QKV projection.
// ---------------------------------------------------------------------------

typedef __bf16 bf16x8 __attribute__((ext_vector_type(8)));
typedef __bf16 bf16x4 __attribute__((ext_vector_type(4)));
typedef float  f32x4  __attribute__((ext_vector_type(4)));

static __device__ __forceinline__ f32x4 mfma16(bf16x8 a, bf16x8 b, f32x4 c) {
  return __builtin_amdgcn_mfma_f32_16x16x32_bf16(a, b, c, 0, 0, 0);
}

// async 16B/lane global->LDS; LDS dest = wave-uniform base + lane*16
static __device__ __forceinline__ void load16_lds(const void* g, void* l) {
  __builtin_amdgcn_global_load_lds(
      (const __attribute__((address_space(1))) unsigned int*)g,
      (__attribute__((address_space(3))) unsigned int*)l, 16, 0, 0);
}

// ---------------------------------------------------------------------------
// fp32 -> bf16, 8 elems/thread
// ---------------------------------------------------------------------------
__global__ __launch_bounds__(256) void cvt_f32_bf16(
    const float* __restrict__ in, __bf16* __restrict__ out, int n8) {
  int i = blockIdx.x * blockDim.x + threadIdx.x;
  if (i >= n8) return;
  const float4* in4 = (const float4*)in;
  float4 a = in4[2 * i], b = in4[2 * i + 1];
  __bf16 v[8];
  v[0] = (__bf16)a.x; v[1] = (__bf16)a.y; v[2] = (__bf16)a.z; v[3] = (__bf16)a.w;
  v[4] = (__bf16)b.x; v[5] = (__bf16)b.y; v[6] = (__bf16)b.z; v[7] = (__bf16)b.w;
  *(bf16x8*)(out + 8 * i) = *(bf16x8*)v;
}

// all 4 weight matrices in one launch: wq,wk,wv -> wqkv rows, wo -> wob
__global__ __launch_bounds__(256) void cvt_w(
    const float* __restrict__ w0, const float* __restrict__ w1,
    const float* __restrict__ w2, const float* __restrict__ w3,
    __bf16* __restrict__ wqkv, __bf16* __restrict__ wo) {
  int blk = blockIdx.x;                 // 2048 blocks, 512 per matrix
  int m = blk >> 9;
  const float* src = (m == 0) ? w0 : (m == 1) ? w1 : (m == 2) ? w2 : w3;
  __bf16* dst = (m < 3) ? (wqkv + (size_t)m * (1024 * 1024)) : wo;
  int i = (blk & 511) * 256 + threadIdx.x;
  const float4* in4 = (const float4*)src;
  float4 a = in4[2 * i], b = in4[2 * i + 1];
  __bf16 v[8];
  v[0] = (__bf16)a.x; v[1] = (__bf16)a.y; v[2] = (__bf16)a.z; v[3] = (__bf16)a.w;
  v[4] = (__bf16)b.x; v[5] = (__bf16)b.y; v[6] = (__bf16)b.z; v[7] = (__bf16)b.w;
  *(bf16x8*)(dst + 8 * i) = *(bf16x8*)v;
}

// ---------------------------------------------------------------------------
// C[M,N] = A[M,K] @ Bw[N,K]^T, m97 pattern: 128x128 tile, BK=32,
// global_load_lds width=16 into unpadded LDS [128][32] with XOR chunk swizzle.
// ---------------------------------------------------------------------------
template <typename OutT>
__global__ __launch_bounds__(256) void gemm_bt2(
    const __bf16* __restrict__ A, const __bf16* __restrict__ Bw,
    OutT* __restrict__ C, int M, int N, int K) {
  __shared__ __align__(16) __bf16 As[128 * 32];
  __shared__ __align__(16) __bf16 Bs[128 * 32];
  const int t = threadIdx.x;
  const int lane = t & 63, w = t >> 6;
  const int wm = w >> 1, wn = w & 1;
  const int l15 = lane & 15, quad = lane >> 4;
  const long rowA0 = (long)blockIdx.y * 128;
  const long rowB0 = (long)blockIdx.x * 128;

  const int r0 = w * 32 + (lane >> 2);
  const int r1 = r0 + 16;
  const int c0 = (lane & 3) ^ ((r0 >> 1) & 3);
  const int c1 = (lane & 3) ^ ((r1 >> 1) & 3);
  const __bf16* pA0 = A + (rowA0 + r0) * (long)K + c0 * 8;
  const __bf16* pA1 = A + (rowA0 + r1) * (long)K + c1 * 8;
  const __bf16* pB0 = Bw + (rowB0 + r0) * (long)K + c0 * 8;
  const __bf16* pB1 = Bw + (rowB0 + r1) * (long)K + c1 * 8;
  __bf16* lA0 = As + (w * 32) * 32;
  __bf16* lA1 = As + (w * 32 + 16) * 32;
  __bf16* lB0 = Bs + (w * 32) * 32;
  __bf16* lB1 = Bs + (w * 32 + 16) * 32;

  int aoff[4], boff[4];
#pragma unroll
  for (int i = 0; i < 4; i++) {
    int Ra = wm * 64 + i * 16 + l15;
    aoff[i] = Ra * 32 + ((quad ^ ((Ra >> 1) & 3)) << 3);
    int Rb = wn * 64 + i * 16 + l15;
    boff[i] = Rb * 32 + ((quad ^ ((Rb >> 1) & 3)) << 3);
  }

  f32x4 acc[4][4] = {};
  for (int k0 = 0; k0 < K; k0 += 32) {
    load16_lds(pA0, lA0); load16_lds(pA1, lA1);
    load16_lds(pB0, lB0); load16_lds(pB1, lB1);
    pA0 += 32; pA1 += 32; pB0 += 32; pB1 += 32;
    __syncthreads();
    bf16x8 af[4], bfr[4];
#pragma unroll
    for (int i = 0; i < 4; i++) af[i] = *(const bf16x8*)(As + aoff[i]);
#pragma unroll
    for (int i = 0; i < 4; i++) bfr[i] = *(const bf16x8*)(Bs + boff[i]);
#pragma unroll
    for (int mt = 0; mt < 4; mt++)
#pragma unroll
      for (int nt = 0; nt < 4; nt++)
        acc[mt][nt] = mfma16(af[mt], bfr[nt], acc[mt][nt]);
    __syncthreads();
  }

#pragma unroll
  for (int mt = 0; mt < 4; mt++)
#pragma unroll
    for (int nt = 0; nt < 4; nt++)
#pragma unroll
      for (int r = 0; r < 4; r++) {
        long row = rowA0 + wm * 64 + mt * 16 + quad * 4 + r;
        long col = rowB0 + wn * 64 + nt * 16 + l15;
        float v = acc[mt][nt][r];
        if constexpr (sizeof(OutT) == 2) C[row * N + col] = (OutT)(__bf16)v;
        else                             C[row * N + col] = v;
      }
}

// ---------------------------------------------------------------------------
// V transpose: QKV[b][s][2048 + h*64 + d] -> VT[(b*16+h)*64 + d][s]
// ---------------------------------------------------------------------------
__global__ __launch_bounds__(256) void vtrans(
    const __bf16* __restrict__ QKV, __bf16* __restrict__ VT) {
  constexpr int LDs = 136;
  __shared__ __align__(16) __bf16 Ts[64 * LDs];
  const int t = threadIdx.x;
  const int st0 = blockIdx.x * 128, h = blockIdx.y, b = blockIdx.z;
  const long vbase = (long)b * 2048 * 3072 + 2048 + h * 64;
#pragma unroll
  for (int i = 0; i < 4; i++) {
    int sl = i * 32 + (t >> 3), d0 = (t & 7) * 8;
    __bf16 tmp[8];
    *(uint4*)tmp = *(const uint4*)(QKV + vbase + (long)(st0 + sl) * 3072 + d0);
#pragma unroll
    for (int j = 0; j < 8; j++) Ts[(d0 + j) * LDs + sl] = tmp[j];
  }
  __syncthreads();
  const long obase = (long)(b * 16 + h) * 64 * 2048 + st0;
  const int d = t >> 2;
#pragma unroll
  for (int i = 0; i < 4; i++) {
    int sc = ((t & 3) + 4 * i) * 8;
    *(uint4*)(VT + obase + (long)d * 2048 + sc) = *(const uint4*)(Ts + d * LDs + sc);
  }
}

// ---------------------------------------------------------------------------
// Causal attention, R6: LDS-staged K/VT shared by all waves.
// Block = pair of 128-row q-tiles (j, 15-j) -> uniform 34 K-tiles/block.
// 512 blocks (8 pairs x 16 h x 4 b), 4 waves x 32 q-rows (mt=0,1).
// Per K-tile (64 keys): stage K[64x64] + VT[64x64] via global_load_lds with
// XOR chunk swizzle (pos = chunk ^ (row&7)); all waves read fragments from
// LDS (ds_read_b128, swizzle-corrected). S^T = K Q^T (lane: key=quad*4+r,
// qrow=l15); no-max exp; packed 8B P writes to wave-private LDS; PV from LDS.
// ---------------------------------------------------------------------------
__global__ __launch_bounds__(256) void attn4(
    const __bf16* __restrict__ QKV, const __bf16* __restrict__ VT,
    __bf16* __restrict__ O) {
  constexpr int SD = 3072;
  constexpr int LDP = 72;
  __shared__ __align__(16) __bf16 Ks[64 * 64];
  __shared__ __align__(16) __bf16 Vs[64 * 64];
  __shared__ __align__(16) __bf16 Pw[4 * 32 * LDP];
  const int t = threadIdx.x;
  const int lane = t & 63, w = t >> 6;
  const int l15 = lane & 15, quad = lane >> 4;
  const int jj = blockIdx.x, h = blockIdx.y, b = blockIdx.z;
  const long qbase = (long)b * 2048 * SD + h * 64;
  const long kbase = qbase + 1024;
  const long vtbase = (long)(b * 16 + h) * 64 * 2048;
  __bf16* Pme = Pw + w * 32 * LDP;

  // staging: wave w covers local rows [w*16, w*16+16) as 2 insts of 8 rows;
  // lane -> row sr (+8 for inst1), fetches global chunk scg, lands at pos lane&7
  const int sr = w * 16 + (lane >> 3);
  const int scg = (lane & 7) ^ (sr & 7);
  __bf16* ldsK0 = Ks + (w * 16) * 64;
  __bf16* ldsK1 = Ks + (w * 16 + 8) * 64;
  __bf16* ldsV0 = Vs + (w * 16) * 64;
  __bf16* ldsV1 = Vs + (w * 16 + 8) * 64;

  // swizzled fragment-read offsets: row R=nt*16+l15, want chunk kk*4+quad,
  // stored at pos (kk*4+quad)^(R&7); R&7 == l15&7
  int kvoff[4][2];
#pragma unroll
  for (int nt = 0; nt < 4; nt++)
#pragma unroll
    for (int kk = 0; kk < 2; kk++)
      kvoff[nt][kk] = (nt * 16 + l15) * 64 + (((kk * 4 + quad) ^ (l15 & 7)) << 3);

#pragma unroll
  for (int half = 0; half < 2; half++) {
    const int qt = half ? (15 - jj) : jj;
    const int q0 = qt * 128;
    const int wrow0 = q0 + w * 32;

    // Q fragments (B-operand: n = qrow = l15), direct global, once per half
    bf16x8 qf[2][2];
#pragma unroll
    for (int mt = 0; mt < 2; mt++)
#pragma unroll
      for (int kk = 0; kk < 2; kk++)
        qf[mt][kk] = *(const bf16x8*)(QKV + qbase +
            (long)(wrow0 + mt * 16 + l15) * SD + kk * 32 + quad * 8);

    f32x4 o_acc[2][4] = {};
    float l_part[2] = {0.f, 0.f};

    const int nkt = 2 * qt + 2;
    for (int kt = 0; kt < nkt; kt++) {
      const int k0 = kt * 64;
      // ---- stage K tile and VT tile (coalesced 16B/lane, swizzled) ----
      load16_lds(QKV + kbase + (long)(k0 + sr) * SD + scg * 8, ldsK0);
      load16_lds(QKV + kbase + (long)(k0 + sr + 8) * SD + scg * 8, ldsK1);
      load16_lds(VT + vtbase + (long)sr * 2048 + k0 + scg * 8, ldsV0);
      load16_lds(VT + vtbase + (long)(sr + 8) * 2048 + k0 + scg * 8, ldsV1);
      __syncthreads();   // compiler emits vmcnt(0) drain before barrier

      if (k0 <= wrow0 + 31) {          // wave has unmasked rows in this tile
        // K fragments (A-operand: m = key)
        bf16x8 kf[4][2];
#pragma unroll
        for (int nt = 0; nt < 4; nt++)
#pragma unroll
          for (int kk = 0; kk < 2; kk++)
            kf[nt][kk] = *(const bf16x8*)(Ks + kvoff[nt][kk]);
        // S^T = K Q^T : lane holds key = nt*16 + quad*4 + r, qrow = l15
        f32x4 st[4][2];
#pragma unroll
        for (int nt = 0; nt < 4; nt++)
#pragma unroll
          for (int mt = 0; mt < 2; mt++) {
            f32x4 z = {0.f, 0.f, 0.f, 0.f};
            z = mfma16(kf[nt][0], qf[mt][0], z);
            st[nt][mt] = mfma16(kf[nt][1], qf[mt][1], z);
          }
        // exp + lane-local l partials + packed P write (4 consec keys, 8B)
        const bool needmask = (k0 + 63 > wrow0);
#pragma unroll
        for (int mt = 0; mt < 2; mt++) {
          const int qrow = wrow0 + mt * 16 + l15;
#pragma unroll
          for (int nt = 0; nt < 4; nt++) {
            const int keyb = k0 + nt * 16 + quad * 4;
            bf16x4 pb;
#pragma unroll
            for (int r = 0; r < 4; r++) {
              float e = __expf(st[nt][mt][r] * 0.125f);
              if (needmask && (keyb + r > qrow)) e = 0.f;
              l_part[mt] += e;
              pb[r] = (__bf16)e;
            }
            *(bf16x4*)(Pme + (mt * 16 + l15) * LDP + nt * 16 + quad * 4) = pb;
          }
        }
        // PV: O += P V (V^T fragments from LDS; B-operand n = d)
#pragma unroll
        for (int kk = 0; kk < 2; kk++) {
          bf16x8 vf[4];
#pragma unroll
          for (int dt = 0; dt < 4; dt++)
            vf[dt] = *(const bf16x8*)(Vs + kvoff[dt][kk]);
#pragma unroll
          for (int mt = 0; mt < 2; mt++) {
            bf16x8 pf = *(const bf16x8*)(Pme + (mt * 16 + l15) * LDP + kk * 32 + quad * 8);
#pragma unroll
            for (int dt = 0; dt < 4; dt++)
              o_acc[mt][dt] = mfma16(pf, vf[dt], o_acc[mt][dt]);
          }
        }
      }
      __syncthreads();   // protect Ks/Vs from next iteration's staging
    }

    // epilogue: l = sum over quads; normalize; write O
#pragma unroll
    for (int mt = 0; mt < 2; mt++) {
      float l = l_part[mt];
      l += __shfl_xor(l, 16, 64);
      l += __shfl_xor(l, 32, 64);        // lane holds l for qrow = l15
#pragma unroll
      for (int r = 0; r < 4; r++) {
        float lr = __shfl(l, quad * 4 + r, 64);
        float inv = 1.f / lr;
        int row = wrow0 + mt * 16 + quad * 4 + r;
        long ob = ((long)b * 2048 + row) * 1024 + h * 64;
#pragma unroll
        for (int dt = 0; dt < 4; dt++)
          O[ob + dt * 16 + l15] = (__bf16)(o_acc[mt][dt][r] * inv);
      }
    }
  }
}

// ---------------------------------------------------------------------------
extern "C" void kernel_launch(void* const* d_in, const int* in_sizes, int n_in,
                              void* d_out, int out_size, void* d_ws, size_t ws_size,
                              hipStream_t stream) {
  const float* x  = (const float*)d_in[0];
  const float* wq = (const float*)d_in[1];
  const float* wk = (const float*)d_in[2];
  const float* wv = (const float*)d_in[3];
  const float* wo = (const float*)d_in[4];
  float* out = (float*)d_out;

  char* ws = (char*)d_ws;
  __bf16* xb   = (__bf16*)(ws);               // 16 MB [8192,1024]; reused as Ab
  __bf16* wqkv = (__bf16*)(ws + (16l << 20)); //  6 MB [3072,1024]
  __bf16* wob  = (__bf16*)(ws + (22l << 20)); //  2 MB
  __bf16* QKV  = (__bf16*)(ws + (24l << 20)); // 48 MB [8192,3072]
  __bf16* VT   = (__bf16*)(ws + (72l << 20)); // 16 MB [4096,2048] -> 88 MB total
  __bf16* Ab   = xb;                          // x dead after QKV gemm

  cvt_f32_bf16<<<4096, 256, 0, stream>>>(x, xb, 8192 * 1024 / 8);
  cvt_w<<<2048, 256, 0, stream>>>(wq, wk, wv, wo, wqkv, wob);

  // fused QKV projection: [8192,3072] = xb @ wqkv^T
  gemm_bt2<__bf16><<<dim3(24, 64), 256, 0, stream>>>(xb, wqkv, QKV, 8192, 3072, 1024);

  // V -> VT [b,h,d,s]
  vtrans<<<dim3(16, 16, 4), 256, 0, stream>>>(QKV, VT);

  // causal attention (paired 128-row tiles, LDS-staged K/VT) -> Ab
  attn4<<<dim3(8, 16, 4), 256, 0, stream>>>(QKV, VT, Ab);

  // output projection (fp32 out)
  gemm_bt2<float><<<dim3(8, 64), 256, 0, stream>>>(Ab, wob, out, 8192, 1024, 1024);
}